// Round 15
// baseline (287.772 us; speedup 1.0000x reference)
//
#include <hip/hip_runtime.h>

#define NB 16
#define LT 4096
#define ND 512
#define MBINS 1024
#define LMBDA 0.1f
#define DLB 8                 // d-channels per fwd block
#define FWD_THREADS 1024

__device__ __forceinline__ float2 cmulf(float2 a, float2 b) {
    return make_float2(a.x * b.x - a.y * b.y, a.x * b.y + a.y * b.x);
}
__device__ __forceinline__ float2 caddf(float2 a, float2 b) { return make_float2(a.x + b.x, a.y + b.y); }
__device__ __forceinline__ float2 csubf(float2 a, float2 b) { return make_float2(a.x - b.x, a.y - b.y); }

// base-4 digit reversal of an 8-bit (4-digit) index
__device__ __forceinline__ int rev4_8(int k) {
    return ((k & 3) << 6) | ((k & 12) << 2) | ((k >> 2) & 12) | ((k >> 6) & 3);
}
// base-4 digit reversal of a 12-bit index (inv kernel)
__device__ __forceinline__ int rev4_12(int t) {
    unsigned r = __brev((unsigned)t) >> 20;
    return (int)(((r & 0x555u) << 1) | ((r >> 1) & 0x555u));
}

// DIF m=1 radix-4 butterfly of rows rbase/8 .. rbase/8+3 (idx units), col dl.
__device__ __forceinline__ void quad_bfly(const float2* zz, int rbase, int dl, float2 y[4]) {
    float2 a0 = zz[rbase + dl];
    float2 a1 = zz[rbase + 8 + dl];
    float2 a2 = zz[rbase + 16 + dl];
    float2 a3 = zz[rbase + 24 + dl];
    float2 t0  = caddf(a0, a2), t1v = csubf(a0, a2);
    float2 t2v = caddf(a1, a3), t3  = csubf(a1, a3);
    y[0] = caddf(t0, t2v);
    y[1] = make_float2(t1v.x + t3.y, t1v.y - t3.x);   // t1 - i*t3
    y[2] = csubf(t0, t2v);
    y[3] = make_float2(t1v.x - t3.y, t1v.y + t3.x);   // t1 + i*t3
}

// ws layout: float [4][NB][MBINS] : 0 -> sum|Qa|^2, 1 -> sum|Qb|^2, 2 -> Re C, 3 -> Im C
// where C = sum_d conj(Qa)*Qb.

// Forward: block = (batch, 8 consecutive d), 1024 threads. Real-pack z = a + i*b.
// == R11 champion == with the m=1 LDS stage FUSED INTO THE COMBINE:
// bin k = 256q + rev4_8(bf) is output q of m=1 butterfly bf (input rows 4bf..4bf+3).
// Thread g's 8 primary bins {g+128j} = quads bfA=rev4_8(g), bfB=rev4_8(g+128);
// its 8 mirror bins = quads at g2=(128-g)&127. Mirror accumulates
// G[j2] = X[3072+g2+128j2] via factor i^{t2} (W4096^3072 = i). Saves 16 ds ops +
// 1 barrier per round; combine reads move to consecutive rows (2x-floor banking).
// Accumulators X1[8]+G[8] = 32 floats (same as R11's X1+Z4 -> no new spill risk).
__global__ __launch_bounds__(FWD_THREADS)
void cte_fwd_kernel(const float* __restrict__ A, const float* __restrict__ Bp,
                    float* __restrict__ ws) {
    __shared__ float2 z[8192];         // [1024 rows][8 cols]; 64 KB
    __shared__ float2 tw[256];         // tw[e] = exp(-2*pi*i*e/1024), e<256; 2 KB

    const int tid = threadIdx.x;
    // XCD-aware swizzle: line-sharing chunk pairs (2c,2c+1) -> same XCD, adjacent slots.
    const int logical = (blockIdx.x & 7) * (gridDim.x >> 3) + (blockIdx.x >> 3);
    const int bb    = logical >> 6;           // 16 batches
    const int chunk = logical & 63;           // 64 d-chunks of 8
    const int d0    = chunk * DLB;

    if (tid < 256) {
        float s, c;
        sincosf(-6.283185307179586f * (float)tid * (1.0f / 1024.0f), &s, &c);
        tw[tid] = make_float2(c, s);
    }

    const int dl  = tid & 7;          // d lane
    const int g   = tid >> 3;         // k-group 0..127
    const int dp  = tid & 3;          // d-pair for the load/stage1 phase
    const int t1l = tid >> 2;         // [0,256): stage-1 butterfly row

    const int g2 = (128 - g) & 127;   // mirror k-group
    const int rA = rev4_8(g)        << 5;   // idx base (32*bf) of quad A
    const int rB = rev4_8(g + 128)  << 5;
    const int rC = rev4_8(g2)       << 5;
    const int rD = rev4_8(g2 + 128) << 5;

    float2 X1[8], G[8];   // X[g+128j] and X[3072 + g2 + 128j]
#pragma unroll
    for (int j = 0; j < 8; ++j) {
        X1[j] = make_float2(0.f, 0.f);
        G[j]  = make_float2(0.f, 0.f);
    }

    for (int t2 = 0; t2 < 4; ++t2) {
        __syncthreads();  // previous round's combine reads of z done; tw valid (round 0)

        // ---- load 4 rows (t1l + 256*it) + radix-4 stage 1 (m=256) in registers ----
        float2 A4[4], B4[4];
#pragma unroll
        for (int it = 0; it < 4; ++it) {
            size_t off = ((size_t)(bb * LT + 4 * (t1l + 256 * it) + t2)) * ND + d0 + 2 * dp;
            A4[it] = *(const float2*)(A + off);
            B4[it] = *(const float2*)(Bp + off);
        }
        {
            float2 w1 = tw[t1l];
            float2 w2 = cmulf(w1, w1);
            float2 w3 = cmulf(w2, w1);
#pragma unroll
            for (int c = 0; c < 2; ++c) {
                float2 x0 = c ? make_float2(A4[0].y, B4[0].y) : make_float2(A4[0].x, B4[0].x);
                float2 x1 = c ? make_float2(A4[1].y, B4[1].y) : make_float2(A4[1].x, B4[1].x);
                float2 x2 = c ? make_float2(A4[2].y, B4[2].y) : make_float2(A4[2].x, B4[2].x);
                float2 x3 = c ? make_float2(A4[3].y, B4[3].y) : make_float2(A4[3].x, B4[3].x);
                float2 t0  = caddf(x0, x2), t1v = csubf(x0, x2);
                float2 t2v = caddf(x1, x3), t3  = csubf(x1, x3);
                float2 y0 = caddf(t0, t2v);
                float2 y2 = cmulf(csubf(t0, t2v), w2);
                float2 y1 = cmulf(make_float2(t1v.x + t3.y, t1v.y - t3.x), w1);  // (t1 - i*t3)*w1
                float2 y3 = cmulf(make_float2(t1v.x - t3.y, t1v.y + t3.x), w3);  // (t1 + i*t3)*w3
                int ix = (t1l << 3) + 2 * dp + c;
                z[ix]        = y0;
                z[ix + 2048] = y1;     // row +256
                z[ix + 4096] = y2;     // row +512
                z[ix + 6144] = y3;     // row +768
            }
        }
        __syncthreads();

        // ---- middle radix-4 DIF stages (m = 64,16,4), batched over 8 d ----
#pragma unroll
        for (int st = 0; st < 3; ++st) {
            const int lgm  = 6 - 2 * st;      // 6,4,2
            const int m    = 1 << lgm;
            const int step = 256 >> lgm;      // 1024/(4m)
#pragma unroll
            for (int r2 = 0; r2 < 2; ++r2) {
                int u   = r2 * FWD_THREADS + tid;  // 2048 work items
                int dli = u & 7;
                int bf  = u >> 3;                  // butterfly id [0,256)
                int j   = bf & (m - 1);
                int i0  = ((bf >> lgm) << (lgm + 2)) + j;
                int ix  = (i0 << 3) + dli;         // rows +m,+2m,+3m -> imm offsets
                float2 a0 = z[ix];
                float2 a1 = z[ix + 8 * m];
                float2 a2 = z[ix + 16 * m];
                float2 a3 = z[ix + 24 * m];
                float2 t0  = caddf(a0, a2), t1v = csubf(a0, a2);
                float2 t2v = caddf(a1, a3), t3  = csubf(a1, a3);
                float2 w1 = tw[j * step];
                float2 w2 = cmulf(w1, w1);
                float2 w3 = cmulf(w2, w1);
                z[ix]          = caddf(t0, t2v);
                z[ix + 8 * m]  = cmulf(make_float2(t1v.x + t3.y, t1v.y - t3.x), w1);
                z[ix + 16 * m] = cmulf(csubf(t0, t2v), w2);
                z[ix + 24 * m] = cmulf(make_float2(t1v.x - t3.y, t1v.y + t3.x), w3);
            }
            __syncthreads();
        }

        // ---- combine with fused m=1 stage (4 quad butterflies in registers) ----
        // X[k] += W4096^(t2 k) Y[k], k = g+128j  (quads A: j even, B: j odd)
        // X[3072+m2] += i^{t2} W4096^(t2 m2) Y[m2], m2 = g2+128j2 (quads C,D)
        float2 wg, w128, w256, vC;
        {
            float s, c;
            sincosf(-1.5339807878856412e-03f * (float)(t2 * g), &s, &c);   // W^(t2 g)
            wg = make_float2(c, s);
            sincosf(-1.9634954084936207e-01f * (float)t2, &s, &c);         // W^(128 t2)
            w128 = make_float2(c, s);
            sincosf(-3.9269908169872414e-01f * (float)t2, &s, &c);         // W^(256 t2)
            w256 = make_float2(c, s);
            sincosf(-1.5339807878856412e-03f * (float)(t2 * g2), &s, &c);  // W^(t2 g2)
            float2 tmir = make_float2(c, s);
            float mix = (t2 & 1) ? 0.f : ((t2 & 2) ? -1.f : 1.f);  // Re i^{t2}
            float miy = (t2 & 1) ? ((t2 & 2) ? -1.f : 1.f) : 0.f;  // Im i^{t2}
            vC = make_float2(mix * tmir.x - miy * tmir.y, mix * tmir.y + miy * tmir.x);
        }
        {
            float2 y[4], wq, p;
            quad_bfly(z, rA, dl, y);          // bins g + 256q  (j = 2q)
            wq = wg;
#pragma unroll
            for (int q = 0; q < 4; ++q) {
                p = cmulf(wq, y[q]);
                X1[2 * q] = caddf(X1[2 * q], p);
                wq = cmulf(wq, w256);
            }
            quad_bfly(z, rB, dl, y);          // bins g + 128 + 256q  (j = 2q+1)
            wq = cmulf(wg, w128);
#pragma unroll
            for (int q = 0; q < 4; ++q) {
                p = cmulf(wq, y[q]);
                X1[2 * q + 1] = caddf(X1[2 * q + 1], p);
                wq = cmulf(wq, w256);
            }
            quad_bfly(z, rC, dl, y);          // mirror bins g2 + 256q  (j2 = 2q)
            wq = vC;
#pragma unroll
            for (int q = 0; q < 4; ++q) {
                p = cmulf(wq, y[q]);
                G[2 * q] = caddf(G[2 * q], p);
                wq = cmulf(wq, w256);
            }
            quad_bfly(z, rD, dl, y);          // mirror bins g2 + 128 + 256q  (j2 = 2q+1)
            wq = cmulf(vC, w128);
#pragma unroll
            for (int q = 0; q < 4; ++q) {
                p = cmulf(wq, y[q]);
                G[2 * q + 1] = caddf(G[2 * q + 1], p);
                wq = cmulf(wq, w256);
            }
        }
    }

    // ---- unpack Qa/Qb, products, reduce over 8 d-lanes, atomic flush ----
#pragma unroll
    for (int j = 0; j < 8; ++j) {
        int k = g + 128 * j;
        float2 P = X1[j];                      // X[k]
        float2 Xm;
        if (k == 0) {
            Xm = P;                            // self-mirror
        } else {
            int j2 = ((1024 - k) - g2) >> 7;   // g>0: 7-j ; g==0: 8-j
            Xm = G[j2];                        // X[4096-k] = X[3072 + g2 + 128 j2]
        }
        float Ar = 0.5f * (P.x + Xm.x);
        float Ai = 0.5f * (P.y - Xm.y);
        float Br = 0.5f * (P.y + Xm.y);
        float Bi = 0.5f * (Xm.x - P.x);
        float da = Ar * Ar + Ai * Ai;
        float db = Br * Br + Bi * Bi;
        float cr = Ar * Br + Ai * Bi;
        float ci = Ar * Bi - Ai * Br;
        for (int msk = 1; msk < DLB; msk <<= 1) {
            da += __shfl_xor(da, msk);
            db += __shfl_xor(db, msk);
            cr += __shfl_xor(cr, msk);
            ci += __shfl_xor(ci, msk);
        }
        if (dl == 0) {
            atomicAdd(&ws[0 * NB * MBINS + bb * MBINS + k], da);
            atomicAdd(&ws[1 * NB * MBINS + bb * MBINS + k], db);
            atomicAdd(&ws[2 * NB * MBINS + bb * MBINS + k], cr);
            atomicAdd(&ws[3 * NB * MBINS + bb * MBINS + k], ci);
        }
    }
}

// Inverse: block = (b, dir). S = C/den (dir 0) or conj(C)/den (dir 1), padded to 4096,
// radix-4 IFFT (conj twiddles, digit-reversed output indexing), real part.
__global__ __launch_bounds__(512)
void cte_inv_kernel(const float* __restrict__ ws, float* __restrict__ out) {
    __shared__ float2 zz[4096];       // 32 KB
    __shared__ float2 tw[1024];       // tw[e] = exp(+2*pi*i*e/4096)
    const int tid = threadIdx.x;
    const int bb  = blockIdx.x >> 1;
    const int dir = blockIdx.x & 1;

    for (int i = tid; i < 1024; i += 512) {
        float s, c;
        sincosf(6.283185307179586f * (float)i * (1.0f / 4096.0f), &s, &c);
        tw[i] = make_float2(c, s);
    }
    for (int i = tid; i < 4096; i += 512) {
        float2 v = make_float2(0.f, 0.f);
        if (i < MBINS) {
            float den = ws[(dir ? 1 : 0) * NB * MBINS + bb * MBINS + i] + LMBDA;
            float cr  = ws[2 * NB * MBINS + bb * MBINS + i];
            float ci  = ws[3 * NB * MBINS + bb * MBINS + i];
            if (dir) ci = -ci;
            v = make_float2(cr / den, ci / den);
        }
        zz[i] = v;
    }
    __syncthreads();

#pragma unroll
    for (int st = 0; st < 6; ++st) {
        const int lgm  = 10 - 2 * st;     // m = 1024,256,64,16,4,1
        const int m    = 1 << lgm;
        const int step = 1024 >> lgm;     // 4096/(4m)
#pragma unroll
        for (int r = 0; r < 2; ++r) {
            int bf = r * 512 + tid;       // butterfly id [0,1024)
            int j  = bf & (m - 1);
            int i0 = ((bf >> lgm) << (lgm + 2)) + j;
            float2 a0 = zz[i0], a1 = zz[i0 + m], a2 = zz[i0 + 2 * m], a3 = zz[i0 + 3 * m];
            float2 t0  = caddf(a0, a2), t1v = csubf(a0, a2);
            float2 t2v = caddf(a1, a3), t3  = csubf(a1, a3);
            float2 y0 = caddf(t0, t2v);
            float2 y2 = csubf(t0, t2v);
            float2 y1 = make_float2(t1v.x - t3.y, t1v.y + t3.x);   // t1 + i*t3 (inverse)
            float2 y3 = make_float2(t1v.x + t3.y, t1v.y - t3.x);   // t1 - i*t3
            if (m > 1) {
                float2 w1 = tw[j * step];
                float2 w2 = cmulf(w1, w1);
                float2 w3 = cmulf(w2, w1);
                y1 = cmulf(y1, w1);
                y2 = cmulf(y2, w2);
                y3 = cmulf(y3, w3);
            }
            zz[i0] = y0; zz[i0 + m] = y1; zz[i0 + 2 * m] = y2; zz[i0 + 3 * m] = y3;
        }
        __syncthreads();
    }

    const float scale = 1.0f / 4096.0f;
    for (int t = tid; t < 4096; t += 512) {
        int rt = rev4_12(t);              // R[t] sits at digit-reversed slot
        float val = zz[rt].x * scale;
        int col = (dir == 0) ? (4095 - t) : (4096 + t);
        out[(size_t)bb * 8192 + col] = val;
    }
}

extern "C" void kernel_launch(void* const* d_in, const int* in_sizes, int n_in,
                              void* d_out, int out_size, void* d_ws, size_t ws_size,
                              hipStream_t stream) {
    const float* a = (const float*)d_in[0];
    const float* b = (const float*)d_in[1];
    // d_in[2] (offsets) only determines shapes; numerically unused.
    float* out = (float*)d_out;
    float* ws  = (float*)d_ws;

    hipMemsetAsync(d_ws, 0, 4 * NB * MBINS * sizeof(float), stream);
    cte_fwd_kernel<<<dim3(NB * (ND / DLB)), dim3(FWD_THREADS), 0, stream>>>(a, b, ws);
    cte_inv_kernel<<<dim3(NB * 2), dim3(512), 0, stream>>>(ws, out);
}

// Round 16
// 196.695 us; speedup vs baseline: 1.4630x; 1.4630x over previous
//
#include <hip/hip_runtime.h>

#define NB 16
#define LT 4096
#define ND 512
#define MBINS 1024
#define LMBDA 0.1f
#define DLB 8                 // d-channels per fwd block
#define FWD_THREADS 1024

__device__ __forceinline__ float2 cmulf(float2 a, float2 b) {
    return make_float2(a.x * b.x - a.y * b.y, a.x * b.y + a.y * b.x);
}
__device__ __forceinline__ float2 caddf(float2 a, float2 b) { return make_float2(a.x + b.x, a.y + b.y); }
__device__ __forceinline__ float2 csubf(float2 a, float2 b) { return make_float2(a.x - b.x, a.y - b.y); }

// base-4 digit reversal of a 10-bit index (bit-reverse, then swap adjacent bit pairs)
__device__ __forceinline__ int rev4_10(int k) {
    unsigned r = __brev((unsigned)k) >> 22;
    return (int)(((r & 0x155u) << 1) | ((r >> 1) & 0x155u));
}
// base-4 digit reversal of a 12-bit index
__device__ __forceinline__ int rev4_12(int t) {
    unsigned r = __brev((unsigned)t) >> 20;
    return (int)(((r & 0x555u) << 1) | ((r >> 1) & 0x555u));
}

// ws layout: float [4][NB][MBINS] : 0 -> sum|Qa|^2, 1 -> sum|Qb|^2, 2 -> Re C, 3 -> Im C
// where C = sum_d conj(Qa)*Qb.

// Forward: block = (batch, 8 consecutive d), 1024 threads. Real-pack z = a + i*b.
// == CHAMPION (R11, 189 us) ==  Structure: stage-1-in-registers, XCD swizzle,
// plain [1024 row][8 col] LDS, 4 LDS stages m=64,16,4,1, incremental-twiddle combine.
// Neighborhood exhausted by experiment: R12 (smaller blocks) -> VGPR-72 occupancy
// cliff; R13 (scatter-write, conflicts 5.2M) -> +1 barrier net loss; R14 (single-pass,
// occupancy 86%) -> L2-granularity loss; R15 (fused m=1, conflicts 4.7M) -> spill.
// Binding constraint: 64-VGPR allocator ceiling at 1024-thread blocks; any added
// liveness spills, any smaller block loses the budget.
__global__ __launch_bounds__(FWD_THREADS)
void cte_fwd_kernel(const float* __restrict__ A, const float* __restrict__ Bp,
                    float* __restrict__ ws) {
    __shared__ float2 z[8192];         // [1024 rows][8 cols]; 64 KB
    __shared__ float2 tw[256];         // tw[e] = exp(-2*pi*i*e/1024), e<256; 2 KB

    const int tid = threadIdx.x;
    // XCD-aware swizzle: line-sharing chunk pairs (2c,2c+1) -> same XCD, adjacent slots.
    const int logical = (blockIdx.x & 7) * (gridDim.x >> 3) + (blockIdx.x >> 3);
    const int bb    = logical >> 6;           // 16 batches
    const int chunk = logical & 63;           // 64 d-chunks of 8
    const int d0    = chunk * DLB;

    if (tid < 256) {
        float s, c;
        sincosf(-6.283185307179586f * (float)tid * (1.0f / 1024.0f), &s, &c);
        tw[tid] = make_float2(c, s);
    }

    const int dl  = tid & 7;          // d lane
    const int g   = tid >> 3;         // k-group 0..127
    const int dp  = tid & 3;          // d-pair for the load/stage1 phase
    const int t1l = tid >> 2;         // [0,256): stage-1 butterfly row

    float2 X1[8], Z4[8];              // X[k] and X[(4096-k)%4096], k = g + 128*j
#pragma unroll
    for (int j = 0; j < 8; ++j) {
        X1[j] = make_float2(0.f, 0.f);
        Z4[j] = make_float2(0.f, 0.f);
    }

    for (int t2 = 0; t2 < 4; ++t2) {
        __syncthreads();  // previous round's combine reads of z done; tw valid (round 0)

        // ---- load 4 rows (t1l + 256*it) + radix-4 stage 1 (m=256) in registers ----
        float2 A4[4], B4[4];
#pragma unroll
        for (int it = 0; it < 4; ++it) {
            size_t off = ((size_t)(bb * LT + 4 * (t1l + 256 * it) + t2)) * ND + d0 + 2 * dp;
            A4[it] = *(const float2*)(A + off);
            B4[it] = *(const float2*)(Bp + off);
        }
        {
            float2 w1 = tw[t1l];
            float2 w2 = cmulf(w1, w1);
            float2 w3 = cmulf(w2, w1);
#pragma unroll
            for (int c = 0; c < 2; ++c) {
                float2 x0 = c ? make_float2(A4[0].y, B4[0].y) : make_float2(A4[0].x, B4[0].x);
                float2 x1 = c ? make_float2(A4[1].y, B4[1].y) : make_float2(A4[1].x, B4[1].x);
                float2 x2 = c ? make_float2(A4[2].y, B4[2].y) : make_float2(A4[2].x, B4[2].x);
                float2 x3 = c ? make_float2(A4[3].y, B4[3].y) : make_float2(A4[3].x, B4[3].x);
                float2 t0  = caddf(x0, x2), t1v = csubf(x0, x2);
                float2 t2v = caddf(x1, x3), t3  = csubf(x1, x3);
                float2 y0 = caddf(t0, t2v);
                float2 y2 = cmulf(csubf(t0, t2v), w2);
                float2 y1 = cmulf(make_float2(t1v.x + t3.y, t1v.y - t3.x), w1);  // (t1 - i*t3)*w1
                float2 y3 = cmulf(make_float2(t1v.x - t3.y, t1v.y + t3.x), w3);  // (t1 + i*t3)*w3
                int ix = (t1l << 3) + 2 * dp + c;
                z[ix]        = y0;
                z[ix + 2048] = y1;     // row +256
                z[ix + 4096] = y2;     // row +512
                z[ix + 6144] = y3;     // row +768
            }
        }
        __syncthreads();

        // ---- remaining radix-4 DIF stages (m = 64,16,4,1), batched over 8 d ----
        // (m=1: j=0, tw[0]=(1,0) -> generic butterfly is exact; completes the FFT.)
#pragma unroll
        for (int st = 0; st < 4; ++st) {
            const int lgm  = 6 - 2 * st;      // 6,4,2,0
            const int m    = 1 << lgm;
            const int step = 256 >> lgm;      // 1024/(4m)
#pragma unroll
            for (int r2 = 0; r2 < 2; ++r2) {
                int u   = r2 * FWD_THREADS + tid;  // 2048 work items
                int dli = u & 7;
                int bf  = u >> 3;                  // butterfly id [0,256)
                int j   = bf & (m - 1);
                int i0  = ((bf >> lgm) << (lgm + 2)) + j;
                int ix  = (i0 << 3) + dli;         // rows +m,+2m,+3m -> imm offsets
                float2 a0 = z[ix];
                float2 a1 = z[ix + 8 * m];
                float2 a2 = z[ix + 16 * m];
                float2 a3 = z[ix + 24 * m];
                float2 t0  = caddf(a0, a2), t1v = csubf(a0, a2);
                float2 t2v = caddf(a1, a3), t3  = csubf(a1, a3);
                float2 w1 = tw[j * step];
                float2 w2 = cmulf(w1, w1);
                float2 w3 = cmulf(w2, w1);
                z[ix]          = caddf(t0, t2v);
                z[ix + 8 * m]  = cmulf(make_float2(t1v.x + t3.y, t1v.y - t3.x), w1);
                z[ix + 16 * m] = cmulf(csubf(t0, t2v), w2);
                z[ix + 24 * m] = cmulf(make_float2(t1v.x - t3.y, t1v.y + t3.x), w3);
            }
            __syncthreads();
        }

        // ---- combine: X[k] += W4096^(t2*k)*Y[k]; X[4096-k] += conj(W)*Y[(1024-k)%1024] ----
        // Incremental twiddle: w(k=g+128j) = w0 * wstep^j (2 sincosf per round)
        float2 w, wstep;
        {
            float s, c;
            sincosf(-1.5339807878856412e-03f * (float)(t2 * g), &s, &c);  // -2pi/4096 * t2*g
            w = make_float2(c, s);
            sincosf(-1.9634954084936207e-01f * (float)t2, &s, &c);        // -2pi/4096 * 128*t2
            wstep = make_float2(c, s);
        }
#pragma unroll
        for (int j = 0; j < 8; ++j) {
            int k   = g + 128 * j;
            int rk  = rev4_10(k);
            int k2  = (1024 - k) & 1023;
            int rk2 = rev4_10(k2);
            float2 Ya = z[(rk << 3) + dl];
            float2 Yb = z[(rk2 << 3) + dl];
            X1[j].x += w.x * Ya.x - w.y * Ya.y;
            X1[j].y += w.x * Ya.y + w.y * Ya.x;
            Z4[j].x += w.x * Yb.x + w.y * Yb.y;   // conj(w) * Yb
            Z4[j].y += w.x * Yb.y - w.y * Yb.x;
            w = cmulf(w, wstep);
        }
    }

    // ---- unpack Qa/Qb, products, reduce over 8 d-lanes, atomic flush ----
#pragma unroll
    for (int j = 0; j < 8; ++j) {
        int k = g + 128 * j;
        float Ar = 0.5f * (X1[j].x + Z4[j].x);
        float Ai = 0.5f * (X1[j].y - Z4[j].y);
        float Br = 0.5f * (X1[j].y + Z4[j].y);
        float Bi = 0.5f * (Z4[j].x - X1[j].x);
        float da = Ar * Ar + Ai * Ai;
        float db = Br * Br + Bi * Bi;
        float cr = Ar * Br + Ai * Bi;
        float ci = Ar * Bi - Ai * Br;
        for (int msk = 1; msk < DLB; msk <<= 1) {
            da += __shfl_xor(da, msk);
            db += __shfl_xor(db, msk);
            cr += __shfl_xor(cr, msk);
            ci += __shfl_xor(ci, msk);
        }
        if (dl == 0) {
            atomicAdd(&ws[0 * NB * MBINS + bb * MBINS + k], da);
            atomicAdd(&ws[1 * NB * MBINS + bb * MBINS + k], db);
            atomicAdd(&ws[2 * NB * MBINS + bb * MBINS + k], cr);
            atomicAdd(&ws[3 * NB * MBINS + bb * MBINS + k], ci);
        }
    }
}

// Inverse: block = (b, dir). S = C/den (dir 0) or conj(C)/den (dir 1), padded to 4096,
// radix-4 IFFT (conj twiddles, digit-reversed output indexing), real part.
__global__ __launch_bounds__(512)
void cte_inv_kernel(const float* __restrict__ ws, float* __restrict__ out) {
    __shared__ float2 zz[4096];       // 32 KB
    __shared__ float2 tw[1024];       // tw[e] = exp(+2*pi*i*e/4096)
    const int tid = threadIdx.x;
    const int bb  = blockIdx.x >> 1;
    const int dir = blockIdx.x & 1;

    for (int i = tid; i < 1024; i += 512) {
        float s, c;
        sincosf(6.283185307179586f * (float)i * (1.0f / 4096.0f), &s, &c);
        tw[i] = make_float2(c, s);
    }
    for (int i = tid; i < 4096; i += 512) {
        float2 v = make_float2(0.f, 0.f);
        if (i < MBINS) {
            float den = ws[(dir ? 1 : 0) * NB * MBINS + bb * MBINS + i] + LMBDA;
            float cr  = ws[2 * NB * MBINS + bb * MBINS + i];
            float ci  = ws[3 * NB * MBINS + bb * MBINS + i];
            if (dir) ci = -ci;
            v = make_float2(cr / den, ci / den);
        }
        zz[i] = v;
    }
    __syncthreads();

#pragma unroll
    for (int st = 0; st < 6; ++st) {
        const int lgm  = 10 - 2 * st;     // m = 1024,256,64,16,4,1
        const int m    = 1 << lgm;
        const int step = 1024 >> lgm;     // 4096/(4m)
#pragma unroll
        for (int r = 0; r < 2; ++r) {
            int bf = r * 512 + tid;       // butterfly id [0,1024)
            int j  = bf & (m - 1);
            int i0 = ((bf >> lgm) << (lgm + 2)) + j;
            float2 a0 = zz[i0], a1 = zz[i0 + m], a2 = zz[i0 + 2 * m], a3 = zz[i0 + 3 * m];
            float2 t0  = caddf(a0, a2), t1v = csubf(a0, a2);
            float2 t2v = caddf(a1, a3), t3  = csubf(a1, a3);
            float2 y0 = caddf(t0, t2v);
            float2 y2 = csubf(t0, t2v);
            float2 y1 = make_float2(t1v.x - t3.y, t1v.y + t3.x);   // t1 + i*t3 (inverse)
            float2 y3 = make_float2(t1v.x + t3.y, t1v.y - t3.x);   // t1 - i*t3
            if (m > 1) {
                float2 w1 = tw[j * step];
                float2 w2 = cmulf(w1, w1);
                float2 w3 = cmulf(w2, w1);
                y1 = cmulf(y1, w1);
                y2 = cmulf(y2, w2);
                y3 = cmulf(y3, w3);
            }
            zz[i0] = y0; zz[i0 + m] = y1; zz[i0 + 2 * m] = y2; zz[i0 + 3 * m] = y3;
        }
        __syncthreads();
    }

    const float scale = 1.0f / 4096.0f;
    for (int t = tid; t < 4096; t += 512) {
        int rt = rev4_12(t);              // R[t] sits at digit-reversed slot
        float val = zz[rt].x * scale;
        int col = (dir == 0) ? (4095 - t) : (4096 + t);
        out[(size_t)bb * 8192 + col] = val;
    }
}

extern "C" void kernel_launch(void* const* d_in, const int* in_sizes, int n_in,
                              void* d_out, int out_size, void* d_ws, size_t ws_size,
                              hipStream_t stream) {
    const float* a = (const float*)d_in[0];
    const float* b = (const float*)d_in[1];
    // d_in[2] (offsets) only determines shapes; numerically unused.
    float* out = (float*)d_out;
    float* ws  = (float*)d_ws;

    hipMemsetAsync(d_ws, 0, 4 * NB * MBINS * sizeof(float), stream);
    cte_fwd_kernel<<<dim3(NB * (ND / DLB)), dim3(FWD_THREADS), 0, stream>>>(a, b, ws);
    cte_inv_kernel<<<dim3(NB * 2), dim3(512), 0, stream>>>(ws, out);
}

// Round 17
// 187.451 us; speedup vs baseline: 1.5352x; 1.0493x over previous
//
#include <hip/hip_runtime.h>

#define NB 16
#define LT 4096
#define ND 512
#define MBINS 1024
#define LMBDA 0.1f
#define DLB 8                 // d-channels per fwd block
#define FWD_THREADS 1024

__device__ __forceinline__ float2 cmulf(float2 a, float2 b) {
    return make_float2(a.x * b.x - a.y * b.y, a.x * b.y + a.y * b.x);
}
__device__ __forceinline__ float2 caddf(float2 a, float2 b) { return make_float2(a.x + b.x, a.y + b.y); }
__device__ __forceinline__ float2 csubf(float2 a, float2 b) { return make_float2(a.x - b.x, a.y - b.y); }

// base-4 digit reversal of a 10-bit index (bit-reverse, then swap adjacent bit pairs)
__device__ __forceinline__ int rev4_10(int k) {
    unsigned r = __brev((unsigned)k) >> 22;
    return (int)(((r & 0x155u) << 1) | ((r >> 1) & 0x155u));
}
// base-4 digit reversal of a 12-bit index
__device__ __forceinline__ int rev4_12(int t) {
    unsigned r = __brev((unsigned)t) >> 20;
    return (int)(((r & 0x555u) << 1) | ((r >> 1) & 0x555u));
}

// ws layout: float [4][NB][MBINS] : 0 -> sum|Qa|^2, 1 -> sum|Qb|^2, 2 -> Re C, 3 -> Im C
// where C = sum_d conj(Qa)*Qb.

// Forward: block = (batch, 8 consecutive d), 1024 threads. Real-pack z = a + i*b.
// == R11 champion + load hoist ==  The round's 8 global loads are issued BEFORE the
// round-top __syncthreads() (they touch only global memory; the barrier protects the
// previous combine's LDS reads). Waves reach the barrier staggered after the combine,
// so load latency drains during the barrier wait instead of stalling stage-1 after it.
// Zero added liveness (A4/B4 live through stage-1 anyway; barrier-time live ~48 < 60
// peak). Everything else identical to the 189-us champion.
// Structural constraint at this point (R12-R15 ledger): 64-VGPR allocator ceiling at
// 1024-thread blocks -- occupancy(R12:cliff), conflicts(R13:+barrier), barriers
// (R14:L2 granularity), LDS-ops(R15:spill) each cost more than they save.
__global__ __launch_bounds__(FWD_THREADS)
void cte_fwd_kernel(const float* __restrict__ A, const float* __restrict__ Bp,
                    float* __restrict__ ws) {
    __shared__ float2 z[8192];         // [1024 rows][8 cols]; 64 KB
    __shared__ float2 tw[256];         // tw[e] = exp(-2*pi*i*e/1024), e<256; 2 KB

    const int tid = threadIdx.x;
    // XCD-aware swizzle: line-sharing chunk pairs (2c,2c+1) -> same XCD, adjacent slots.
    const int logical = (blockIdx.x & 7) * (gridDim.x >> 3) + (blockIdx.x >> 3);
    const int bb    = logical >> 6;           // 16 batches
    const int chunk = logical & 63;           // 64 d-chunks of 8
    const int d0    = chunk * DLB;

    if (tid < 256) {
        float s, c;
        sincosf(-6.283185307179586f * (float)tid * (1.0f / 1024.0f), &s, &c);
        tw[tid] = make_float2(c, s);
    }

    const int dl  = tid & 7;          // d lane
    const int g   = tid >> 3;         // k-group 0..127
    const int dp  = tid & 3;          // d-pair for the load/stage1 phase
    const int t1l = tid >> 2;         // [0,256): stage-1 butterfly row

    float2 X1[8], Z4[8];              // X[k] and X[(4096-k)%4096], k = g + 128*j
#pragma unroll
    for (int j = 0; j < 8; ++j) {
        X1[j] = make_float2(0.f, 0.f);
        Z4[j] = make_float2(0.f, 0.f);
    }

    for (int t2 = 0; t2 < 4; ++t2) {
        // ---- issue this round's global loads BEFORE the barrier (latency drains
        //      while waiting for the last wave of the previous combine) ----
        float2 A4[4], B4[4];
#pragma unroll
        for (int it = 0; it < 4; ++it) {
            size_t off = ((size_t)(bb * LT + 4 * (t1l + 256 * it) + t2)) * ND + d0 + 2 * dp;
            A4[it] = *(const float2*)(A + off);
            B4[it] = *(const float2*)(Bp + off);
        }

        __syncthreads();  // previous round's combine reads of z done; tw valid (round 0)

        // ---- radix-4 stage 1 (m=256) in registers ----
        {
            float2 w1 = tw[t1l];
            float2 w2 = cmulf(w1, w1);
            float2 w3 = cmulf(w2, w1);
#pragma unroll
            for (int c = 0; c < 2; ++c) {
                float2 x0 = c ? make_float2(A4[0].y, B4[0].y) : make_float2(A4[0].x, B4[0].x);
                float2 x1 = c ? make_float2(A4[1].y, B4[1].y) : make_float2(A4[1].x, B4[1].x);
                float2 x2 = c ? make_float2(A4[2].y, B4[2].y) : make_float2(A4[2].x, B4[2].x);
                float2 x3 = c ? make_float2(A4[3].y, B4[3].y) : make_float2(A4[3].x, B4[3].x);
                float2 t0  = caddf(x0, x2), t1v = csubf(x0, x2);
                float2 t2v = caddf(x1, x3), t3  = csubf(x1, x3);
                float2 y0 = caddf(t0, t2v);
                float2 y2 = cmulf(csubf(t0, t2v), w2);
                float2 y1 = cmulf(make_float2(t1v.x + t3.y, t1v.y - t3.x), w1);  // (t1 - i*t3)*w1
                float2 y3 = cmulf(make_float2(t1v.x - t3.y, t1v.y + t3.x), w3);  // (t1 + i*t3)*w3
                int ix = (t1l << 3) + 2 * dp + c;
                z[ix]        = y0;
                z[ix + 2048] = y1;     // row +256
                z[ix + 4096] = y2;     // row +512
                z[ix + 6144] = y3;     // row +768
            }
        }
        __syncthreads();

        // ---- remaining radix-4 DIF stages (m = 64,16,4,1), batched over 8 d ----
        // (m=1: j=0, tw[0]=(1,0) -> generic butterfly is exact; completes the FFT.)
#pragma unroll
        for (int st = 0; st < 4; ++st) {
            const int lgm  = 6 - 2 * st;      // 6,4,2,0
            const int m    = 1 << lgm;
            const int step = 256 >> lgm;      // 1024/(4m)
#pragma unroll
            for (int r2 = 0; r2 < 2; ++r2) {
                int u   = r2 * FWD_THREADS + tid;  // 2048 work items
                int dli = u & 7;
                int bf  = u >> 3;                  // butterfly id [0,256)
                int j   = bf & (m - 1);
                int i0  = ((bf >> lgm) << (lgm + 2)) + j;
                int ix  = (i0 << 3) + dli;         // rows +m,+2m,+3m -> imm offsets
                float2 a0 = z[ix];
                float2 a1 = z[ix + 8 * m];
                float2 a2 = z[ix + 16 * m];
                float2 a3 = z[ix + 24 * m];
                float2 t0  = caddf(a0, a2), t1v = csubf(a0, a2);
                float2 t2v = caddf(a1, a3), t3  = csubf(a1, a3);
                float2 w1 = tw[j * step];
                float2 w2 = cmulf(w1, w1);
                float2 w3 = cmulf(w2, w1);
                z[ix]          = caddf(t0, t2v);
                z[ix + 8 * m]  = cmulf(make_float2(t1v.x + t3.y, t1v.y - t3.x), w1);
                z[ix + 16 * m] = cmulf(csubf(t0, t2v), w2);
                z[ix + 24 * m] = cmulf(make_float2(t1v.x - t3.y, t1v.y + t3.x), w3);
            }
            __syncthreads();
        }

        // ---- combine: X[k] += W4096^(t2*k)*Y[k]; X[4096-k] += conj(W)*Y[(1024-k)%1024] ----
        // Incremental twiddle: w(k=g+128j) = w0 * wstep^j (2 sincosf per round)
        float2 w, wstep;
        {
            float s, c;
            sincosf(-1.5339807878856412e-03f * (float)(t2 * g), &s, &c);  // -2pi/4096 * t2*g
            w = make_float2(c, s);
            sincosf(-1.9634954084936207e-01f * (float)t2, &s, &c);        // -2pi/4096 * 128*t2
            wstep = make_float2(c, s);
        }
#pragma unroll
        for (int j = 0; j < 8; ++j) {
            int k   = g + 128 * j;
            int rk  = rev4_10(k);
            int k2  = (1024 - k) & 1023;
            int rk2 = rev4_10(k2);
            float2 Ya = z[(rk << 3) + dl];
            float2 Yb = z[(rk2 << 3) + dl];
            X1[j].x += w.x * Ya.x - w.y * Ya.y;
            X1[j].y += w.x * Ya.y + w.y * Ya.x;
            Z4[j].x += w.x * Yb.x + w.y * Yb.y;   // conj(w) * Yb
            Z4[j].y += w.x * Yb.y - w.y * Yb.x;
            w = cmulf(w, wstep);
        }
    }

    // ---- unpack Qa/Qb, products, reduce over 8 d-lanes, atomic flush ----
#pragma unroll
    for (int j = 0; j < 8; ++j) {
        int k = g + 128 * j;
        float Ar = 0.5f * (X1[j].x + Z4[j].x);
        float Ai = 0.5f * (X1[j].y - Z4[j].y);
        float Br = 0.5f * (X1[j].y + Z4[j].y);
        float Bi = 0.5f * (Z4[j].x - X1[j].x);
        float da = Ar * Ar + Ai * Ai;
        float db = Br * Br + Bi * Bi;
        float cr = Ar * Br + Ai * Bi;
        float ci = Ar * Bi - Ai * Br;
        for (int msk = 1; msk < DLB; msk <<= 1) {
            da += __shfl_xor(da, msk);
            db += __shfl_xor(db, msk);
            cr += __shfl_xor(cr, msk);
            ci += __shfl_xor(ci, msk);
        }
        if (dl == 0) {
            atomicAdd(&ws[0 * NB * MBINS + bb * MBINS + k], da);
            atomicAdd(&ws[1 * NB * MBINS + bb * MBINS + k], db);
            atomicAdd(&ws[2 * NB * MBINS + bb * MBINS + k], cr);
            atomicAdd(&ws[3 * NB * MBINS + bb * MBINS + k], ci);
        }
    }
}

// Inverse: block = (b, dir). S = C/den (dir 0) or conj(C)/den (dir 1), padded to 4096,
// radix-4 IFFT (conj twiddles, digit-reversed output indexing), real part.
__global__ __launch_bounds__(512)
void cte_inv_kernel(const float* __restrict__ ws, float* __restrict__ out) {
    __shared__ float2 zz[4096];       // 32 KB
    __shared__ float2 tw[1024];       // tw[e] = exp(+2*pi*i*e/4096)
    const int tid = threadIdx.x;
    const int bb  = blockIdx.x >> 1;
    const int dir = blockIdx.x & 1;

    for (int i = tid; i < 1024; i += 512) {
        float s, c;
        sincosf(6.283185307179586f * (float)i * (1.0f / 4096.0f), &s, &c);
        tw[i] = make_float2(c, s);
    }
    for (int i = tid; i < 4096; i += 512) {
        float2 v = make_float2(0.f, 0.f);
        if (i < MBINS) {
            float den = ws[(dir ? 1 : 0) * NB * MBINS + bb * MBINS + i] + LMBDA;
            float cr  = ws[2 * NB * MBINS + bb * MBINS + i];
            float ci  = ws[3 * NB * MBINS + bb * MBINS + i];
            if (dir) ci = -ci;
            v = make_float2(cr / den, ci / den);
        }
        zz[i] = v;
    }
    __syncthreads();

#pragma unroll
    for (int st = 0; st < 6; ++st) {
        const int lgm  = 10 - 2 * st;     // m = 1024,256,64,16,4,1
        const int m    = 1 << lgm;
        const int step = 1024 >> lgm;     // 4096/(4m)
#pragma unroll
        for (int r = 0; r < 2; ++r) {
            int bf = r * 512 + tid;       // butterfly id [0,1024)
            int j  = bf & (m - 1);
            int i0 = ((bf >> lgm) << (lgm + 2)) + j;
            float2 a0 = zz[i0], a1 = zz[i0 + m], a2 = zz[i0 + 2 * m], a3 = zz[i0 + 3 * m];
            float2 t0  = caddf(a0, a2), t1v = csubf(a0, a2);
            float2 t2v = caddf(a1, a3), t3  = csubf(a1, a3);
            float2 y0 = caddf(t0, t2v);
            float2 y2 = csubf(t0, t2v);
            float2 y1 = make_float2(t1v.x - t3.y, t1v.y + t3.x);   // t1 + i*t3 (inverse)
            float2 y3 = make_float2(t1v.x + t3.y, t1v.y - t3.x);   // t1 - i*t3
            if (m > 1) {
                float2 w1 = tw[j * step];
                float2 w2 = cmulf(w1, w1);
                float2 w3 = cmulf(w2, w1);
                y1 = cmulf(y1, w1);
                y2 = cmulf(y2, w2);
                y3 = cmulf(y3, w3);
            }
            zz[i0] = y0; zz[i0 + m] = y1; zz[i0 + 2 * m] = y2; zz[i0 + 3 * m] = y3;
        }
        __syncthreads();
    }

    const float scale = 1.0f / 4096.0f;
    for (int t = tid; t < 4096; t += 512) {
        int rt = rev4_12(t);              // R[t] sits at digit-reversed slot
        float val = zz[rt].x * scale;
        int col = (dir == 0) ? (4095 - t) : (4096 + t);
        out[(size_t)bb * 8192 + col] = val;
    }
}

extern "C" void kernel_launch(void* const* d_in, const int* in_sizes, int n_in,
                              void* d_out, int out_size, void* d_ws, size_t ws_size,
                              hipStream_t stream) {
    const float* a = (const float*)d_in[0];
    const float* b = (const float*)d_in[1];
    // d_in[2] (offsets) only determines shapes; numerically unused.
    float* out = (float*)d_out;
    float* ws  = (float*)d_ws;

    hipMemsetAsync(d_ws, 0, 4 * NB * MBINS * sizeof(float), stream);
    cte_fwd_kernel<<<dim3(NB * (ND / DLB)), dim3(FWD_THREADS), 0, stream>>>(a, b, ws);
    cte_inv_kernel<<<dim3(NB * 2), dim3(512), 0, stream>>>(ws, out);
}

// Round 18
// 178.228 us; speedup vs baseline: 1.6146x; 1.0517x over previous
//
#include <hip/hip_runtime.h>

#define NB 16
#define LT 4096
#define ND 512
#define MBINS 1024
#define LMBDA 0.1f
#define DLB 8                 // d-channels per fwd block
#define FWD_THREADS 1024

__device__ __forceinline__ float2 cmulf(float2 a, float2 b) {
    return make_float2(a.x * b.x - a.y * b.y, a.x * b.y + a.y * b.x);
}
__device__ __forceinline__ float2 caddf(float2 a, float2 b) { return make_float2(a.x + b.x, a.y + b.y); }
__device__ __forceinline__ float2 csubf(float2 a, float2 b) { return make_float2(a.x - b.x, a.y - b.y); }

// base-4 digit reversal of a 10-bit index (bit-reverse, then swap adjacent bit pairs)
__device__ __forceinline__ int rev4_10(int k) {
    unsigned r = __brev((unsigned)k) >> 22;
    return (int)(((r & 0x155u) << 1) | ((r >> 1) & 0x155u));
}
// base-4 digit reversal of a 12-bit index
__device__ __forceinline__ int rev4_12(int t) {
    unsigned r = __brev((unsigned)t) >> 20;
    return (int)(((r & 0x555u) << 1) | ((r >> 1) & 0x555u));
}

// ws layout: float [4][NB][MBINS] : 0 -> sum|Qa|^2, 1 -> sum|Qb|^2, 2 -> Re C, 3 -> Im C
// where C = sum_d conj(Qa)*Qb.

// Forward: block = (batch, 8 consecutive d), 1024 threads. Real-pack z = a + i*b.
// == R17 champion (187 us: R11 + load hoist) + two VALU/LDS-issue shavings ==
//  (a) combine twiddles w0 = W4096^(t2 g) from a precomputed tw2[512] LDS table and
//      wstep = W4096^(128 t2) = tw[32 t2] -- removes all 8 per-thread sincosf calls
//      from the round loop (~200 VALU ops/thread, the only transcendentals left).
//  (b) stage-1 writes as float4: t-values for both c computed first (x's die before
//      y's are built -> peak liveness ~58 < 64, unlike R15's fused spill), then the
//      adjacent cols 2dp/2dp+1 merge into 4 ds_write_b128 at the bank floor.
// Structural constraint (R12-R15 ledger): 64-VGPR allocator ceiling at 1024-thread
// blocks -- occupancy(R12:cliff), conflicts(R13:+barrier), barriers(R14:L2
// granularity), LDS-ops(R15:spill) each cost more than they save.
__global__ __launch_bounds__(FWD_THREADS)
void cte_fwd_kernel(const float* __restrict__ A, const float* __restrict__ Bp,
                    float* __restrict__ ws) {
    __shared__ __align__(16) float2 z[8192];   // [1024 rows][8 cols]; 64 KB
    __shared__ float2 tw[256];         // tw[e] = exp(-2*pi*i*e/1024), e<256; 2 KB
    __shared__ float2 tw2[512];        // tw2[128*t2+g] = exp(-2*pi*i*(t2*g)/4096); 4 KB

    const int tid = threadIdx.x;
    // XCD-aware swizzle: line-sharing chunk pairs (2c,2c+1) -> same XCD, adjacent slots.
    const int logical = (blockIdx.x & 7) * (gridDim.x >> 3) + (blockIdx.x >> 3);
    const int bb    = logical >> 6;           // 16 batches
    const int chunk = logical & 63;           // 64 d-chunks of 8
    const int d0    = chunk * DLB;

    if (tid < 256) {
        float s, c;
        sincosf(-6.283185307179586f * (float)tid * (1.0f / 1024.0f), &s, &c);
        tw[tid] = make_float2(c, s);
    }
    if (tid < 512) {
        int t2i = tid >> 7, gi = tid & 127;
        float s, c;
        sincosf(-1.5339807878856412e-03f * (float)(t2i * gi), &s, &c);  // -2pi/4096 * t2*g
        tw2[tid] = make_float2(c, s);
    }

    const int dl  = tid & 7;          // d lane
    const int g   = tid >> 3;         // k-group 0..127
    const int dp  = tid & 3;          // d-pair for the load/stage1 phase
    const int t1l = tid >> 2;         // [0,256): stage-1 butterfly row

    float2 X1[8], Z4[8];              // X[k] and X[(4096-k)%4096], k = g + 128*j
#pragma unroll
    for (int j = 0; j < 8; ++j) {
        X1[j] = make_float2(0.f, 0.f);
        Z4[j] = make_float2(0.f, 0.f);
    }

    for (int t2 = 0; t2 < 4; ++t2) {
        // ---- issue this round's global loads BEFORE the barrier (latency drains
        //      while waiting for the last wave of the previous combine) ----
        float2 A4[4], B4[4];
#pragma unroll
        for (int it = 0; it < 4; ++it) {
            size_t off = ((size_t)(bb * LT + 4 * (t1l + 256 * it) + t2)) * ND + d0 + 2 * dp;
            A4[it] = *(const float2*)(A + off);
            B4[it] = *(const float2*)(Bp + off);
        }

        __syncthreads();  // previous round's combine reads of z done; tw/tw2 valid (rd 0)

        // ---- radix-4 stage 1 (m=256) in registers; float4 writes ----
        {
            float2 w1 = tw[t1l];
            float2 w2 = cmulf(w1, w1);
            float2 w3 = cmulf(w2, w1);
            float2 T0[2], T1[2], T2[2], T3[2];
#pragma unroll
            for (int c = 0; c < 2; ++c) {
                float2 x0 = c ? make_float2(A4[0].y, B4[0].y) : make_float2(A4[0].x, B4[0].x);
                float2 x1 = c ? make_float2(A4[1].y, B4[1].y) : make_float2(A4[1].x, B4[1].x);
                float2 x2 = c ? make_float2(A4[2].y, B4[2].y) : make_float2(A4[2].x, B4[2].x);
                float2 x3 = c ? make_float2(A4[3].y, B4[3].y) : make_float2(A4[3].x, B4[3].x);
                T0[c] = caddf(x0, x2);  T1[c] = csubf(x0, x2);
                T2[c] = caddf(x1, x3);  T3[c] = csubf(x1, x3);
            }
            const int ix = (t1l << 3) + 2 * dp;   // even float2 index -> 16B aligned
            {   // row +0: y0 = t0 + t2
                float2 ya = caddf(T0[0], T2[0]);
                float2 yb = caddf(T0[1], T2[1]);
                *(float4*)&z[ix] = make_float4(ya.x, ya.y, yb.x, yb.y);
            }
            {   // row +256: y1 = (t1 - i*t3) * w1
                float2 ya = cmulf(make_float2(T1[0].x + T3[0].y, T1[0].y - T3[0].x), w1);
                float2 yb = cmulf(make_float2(T1[1].x + T3[1].y, T1[1].y - T3[1].x), w1);
                *(float4*)&z[ix + 2048] = make_float4(ya.x, ya.y, yb.x, yb.y);
            }
            {   // row +512: y2 = (t0 - t2) * w2
                float2 ya = cmulf(csubf(T0[0], T2[0]), w2);
                float2 yb = cmulf(csubf(T0[1], T2[1]), w2);
                *(float4*)&z[ix + 4096] = make_float4(ya.x, ya.y, yb.x, yb.y);
            }
            {   // row +768: y3 = (t1 + i*t3) * w3
                float2 ya = cmulf(make_float2(T1[0].x - T3[0].y, T1[0].y + T3[0].x), w3);
                float2 yb = cmulf(make_float2(T1[1].x - T3[1].y, T1[1].y + T3[1].x), w3);
                *(float4*)&z[ix + 6144] = make_float4(ya.x, ya.y, yb.x, yb.y);
            }
        }
        __syncthreads();

        // ---- remaining radix-4 DIF stages (m = 64,16,4,1), batched over 8 d ----
        // (m=1: j=0, tw[0]=(1,0) -> generic butterfly is exact; completes the FFT.)
#pragma unroll
        for (int st = 0; st < 4; ++st) {
            const int lgm  = 6 - 2 * st;      // 6,4,2,0
            const int m    = 1 << lgm;
            const int step = 256 >> lgm;      // 1024/(4m)
#pragma unroll
            for (int r2 = 0; r2 < 2; ++r2) {
                int u   = r2 * FWD_THREADS + tid;  // 2048 work items
                int dli = u & 7;
                int bf  = u >> 3;                  // butterfly id [0,256)
                int j   = bf & (m - 1);
                int i0  = ((bf >> lgm) << (lgm + 2)) + j;
                int ix  = (i0 << 3) + dli;         // rows +m,+2m,+3m -> imm offsets
                float2 a0 = z[ix];
                float2 a1 = z[ix + 8 * m];
                float2 a2 = z[ix + 16 * m];
                float2 a3 = z[ix + 24 * m];
                float2 t0  = caddf(a0, a2), t1v = csubf(a0, a2);
                float2 t2v = caddf(a1, a3), t3  = csubf(a1, a3);
                float2 w1 = tw[j * step];
                float2 w2 = cmulf(w1, w1);
                float2 w3 = cmulf(w2, w1);
                z[ix]          = caddf(t0, t2v);
                z[ix + 8 * m]  = cmulf(make_float2(t1v.x + t3.y, t1v.y - t3.x), w1);
                z[ix + 16 * m] = cmulf(csubf(t0, t2v), w2);
                z[ix + 24 * m] = cmulf(make_float2(t1v.x - t3.y, t1v.y + t3.x), w3);
            }
            __syncthreads();
        }

        // ---- combine: X[k] += W4096^(t2*k)*Y[k]; X[4096-k] += conj(W)*Y[(1024-k)%1024] ----
        // Twiddles from tables: w0 = tw2[128 t2 + g], wstep = W4096^(128 t2) = tw[32 t2].
        float2 w     = tw2[(t2 << 7) + g];
        float2 wstep = tw[t2 << 5];
#pragma unroll
        for (int j = 0; j < 8; ++j) {
            int k   = g + 128 * j;
            int rk  = rev4_10(k);
            int k2  = (1024 - k) & 1023;
            int rk2 = rev4_10(k2);
            float2 Ya = z[(rk << 3) + dl];
            float2 Yb = z[(rk2 << 3) + dl];
            X1[j].x += w.x * Ya.x - w.y * Ya.y;
            X1[j].y += w.x * Ya.y + w.y * Ya.x;
            Z4[j].x += w.x * Yb.x + w.y * Yb.y;   // conj(w) * Yb
            Z4[j].y += w.x * Yb.y - w.y * Yb.x;
            w = cmulf(w, wstep);
        }
    }

    // ---- unpack Qa/Qb, products, reduce over 8 d-lanes, atomic flush ----
#pragma unroll
    for (int j = 0; j < 8; ++j) {
        int k = g + 128 * j;
        float Ar = 0.5f * (X1[j].x + Z4[j].x);
        float Ai = 0.5f * (X1[j].y - Z4[j].y);
        float Br = 0.5f * (X1[j].y + Z4[j].y);
        float Bi = 0.5f * (Z4[j].x - X1[j].x);
        float da = Ar * Ar + Ai * Ai;
        float db = Br * Br + Bi * Bi;
        float cr = Ar * Br + Ai * Bi;
        float ci = Ar * Bi - Ai * Br;
        for (int msk = 1; msk < DLB; msk <<= 1) {
            da += __shfl_xor(da, msk);
            db += __shfl_xor(db, msk);
            cr += __shfl_xor(cr, msk);
            ci += __shfl_xor(ci, msk);
        }
        if (dl == 0) {
            atomicAdd(&ws[0 * NB * MBINS + bb * MBINS + k], da);
            atomicAdd(&ws[1 * NB * MBINS + bb * MBINS + k], db);
            atomicAdd(&ws[2 * NB * MBINS + bb * MBINS + k], cr);
            atomicAdd(&ws[3 * NB * MBINS + bb * MBINS + k], ci);
        }
    }
}

// Inverse: block = (b, dir). S = C/den (dir 0) or conj(C)/den (dir 1), padded to 4096,
// radix-4 IFFT (conj twiddles, digit-reversed output indexing), real part.
__global__ __launch_bounds__(512)
void cte_inv_kernel(const float* __restrict__ ws, float* __restrict__ out) {
    __shared__ float2 zz[4096];       // 32 KB
    __shared__ float2 tw[1024];       // tw[e] = exp(+2*pi*i*e/4096)
    const int tid = threadIdx.x;
    const int bb  = blockIdx.x >> 1;
    const int dir = blockIdx.x & 1;

    for (int i = tid; i < 1024; i += 512) {
        float s, c;
        sincosf(6.283185307179586f * (float)i * (1.0f / 4096.0f), &s, &c);
        tw[i] = make_float2(c, s);
    }
    for (int i = tid; i < 4096; i += 512) {
        float2 v = make_float2(0.f, 0.f);
        if (i < MBINS) {
            float den = ws[(dir ? 1 : 0) * NB * MBINS + bb * MBINS + i] + LMBDA;
            float cr  = ws[2 * NB * MBINS + bb * MBINS + i];
            float ci  = ws[3 * NB * MBINS + bb * MBINS + i];
            if (dir) ci = -ci;
            v = make_float2(cr / den, ci / den);
        }
        zz[i] = v;
    }
    __syncthreads();

#pragma unroll
    for (int st = 0; st < 6; ++st) {
        const int lgm  = 10 - 2 * st;     // m = 1024,256,64,16,4,1
        const int m    = 1 << lgm;
        const int step = 1024 >> lgm;     // 4096/(4m)
#pragma unroll
        for (int r = 0; r < 2; ++r) {
            int bf = r * 512 + tid;       // butterfly id [0,1024)
            int j  = bf & (m - 1);
            int i0 = ((bf >> lgm) << (lgm + 2)) + j;
            float2 a0 = zz[i0], a1 = zz[i0 + m], a2 = zz[i0 + 2 * m], a3 = zz[i0 + 3 * m];
            float2 t0  = caddf(a0, a2), t1v = csubf(a0, a2);
            float2 t2v = caddf(a1, a3), t3  = csubf(a1, a3);
            float2 y0 = caddf(t0, t2v);
            float2 y2 = csubf(t0, t2v);
            float2 y1 = make_float2(t1v.x - t3.y, t1v.y + t3.x);   // t1 + i*t3 (inverse)
            float2 y3 = make_float2(t1v.x + t3.y, t1v.y - t3.x);   // t1 - i*t3
            if (m > 1) {
                float2 w1 = tw[j * step];
                float2 w2 = cmulf(w1, w1);
                float2 w3 = cmulf(w2, w1);
                y1 = cmulf(y1, w1);
                y2 = cmulf(y2, w2);
                y3 = cmulf(y3, w3);
            }
            zz[i0] = y0; zz[i0 + m] = y1; zz[i0 + 2 * m] = y2; zz[i0 + 3 * m] = y3;
        }
        __syncthreads();
    }

    const float scale = 1.0f / 4096.0f;
    for (int t = tid; t < 4096; t += 512) {
        int rt = rev4_12(t);              // R[t] sits at digit-reversed slot
        float val = zz[rt].x * scale;
        int col = (dir == 0) ? (4095 - t) : (4096 + t);
        out[(size_t)bb * 8192 + col] = val;
    }
}

extern "C" void kernel_launch(void* const* d_in, const int* in_sizes, int n_in,
                              void* d_out, int out_size, void* d_ws, size_t ws_size,
                              hipStream_t stream) {
    const float* a = (const float*)d_in[0];
    const float* b = (const float*)d_in[1];
    // d_in[2] (offsets) only determines shapes; numerically unused.
    float* out = (float*)d_out;
    float* ws  = (float*)d_ws;

    hipMemsetAsync(d_ws, 0, 4 * NB * MBINS * sizeof(float), stream);
    cte_fwd_kernel<<<dim3(NB * (ND / DLB)), dim3(FWD_THREADS), 0, stream>>>(a, b, ws);
    cte_inv_kernel<<<dim3(NB * 2), dim3(512), 0, stream>>>(ws, out);
}

// Round 19
// 172.883 us; speedup vs baseline: 1.6645x; 1.0309x over previous
//
#include <hip/hip_runtime.h>

#define NB 16
#define LT 4096
#define ND 512
#define MBINS 1024
#define LMBDA 0.1f
#define DLB 8                 // d-channels per fwd block
#define FWD_THREADS 1024

__device__ __forceinline__ float2 cmulf(float2 a, float2 b) {
    return make_float2(a.x * b.x - a.y * b.y, a.x * b.y + a.y * b.x);
}
__device__ __forceinline__ float2 caddf(float2 a, float2 b) { return make_float2(a.x + b.x, a.y + b.y); }
__device__ __forceinline__ float2 csubf(float2 a, float2 b) { return make_float2(a.x - b.x, a.y - b.y); }

// base-4 digit reversal of a 10-bit index (bit-reverse, then swap adjacent bit pairs)
__device__ __forceinline__ int rev4_10(int k) {
    unsigned r = __brev((unsigned)k) >> 22;
    return (int)(((r & 0x155u) << 1) | ((r >> 1) & 0x155u));
}
// base-4 digit reversal of a 12-bit index
__device__ __forceinline__ int rev4_12(int t) {
    unsigned r = __brev((unsigned)t) >> 20;
    return (int)(((r & 0x555u) << 1) | ((r >> 1) & 0x555u));
}

// ws layout: float [4][NB][MBINS] : 0 -> sum|Qa|^2, 1 -> sum|Qb|^2, 2 -> Re C, 3 -> Im C
// where C = sum_d conj(Qa)*Qb.

// Forward: block = (batch, 8 consecutive d), 1024 threads. Real-pack z = a + i*b.
// == R18 champion (178 us) + b128 middle stages ==
// Middle stages restructured to ONE float4 butterfly per thread (bfm = tid>>2,
// col-pair dp2 = tid&3; 256 bf x 4 pairs = 1024 items): 4 b128 reads + 4 b128
// writes per stage vs 8+8 b64 -- half the LDS instructions, w2/w3 computed once
// per butterfly. Wave covers 16 consecutive bfm -> contiguous 1024B per access
// (bank floor). Liveness discipline as stage-1: a's die into t's, per-row y's
// transient; peak ~60 < 64.
// Structural constraint (R12-R15 ledger): 64-VGPR allocator ceiling at 1024-thread
// blocks -- occupancy(R12:cliff), conflicts(R13:+barrier), barriers(R14:L2
// granularity), LDS-ops-with-added-liveness(R15:spill) each cost more than they save.
__global__ __launch_bounds__(FWD_THREADS)
void cte_fwd_kernel(const float* __restrict__ A, const float* __restrict__ Bp,
                    float* __restrict__ ws) {
    __shared__ __align__(16) float2 z[8192];   // [1024 rows][8 cols]; 64 KB
    __shared__ float2 tw[256];         // tw[e] = exp(-2*pi*i*e/1024), e<256; 2 KB
    __shared__ float2 tw2[512];        // tw2[128*t2+g] = exp(-2*pi*i*(t2*g)/4096); 4 KB

    const int tid = threadIdx.x;
    // XCD-aware swizzle: line-sharing chunk pairs (2c,2c+1) -> same XCD, adjacent slots.
    const int logical = (blockIdx.x & 7) * (gridDim.x >> 3) + (blockIdx.x >> 3);
    const int bb    = logical >> 6;           // 16 batches
    const int chunk = logical & 63;           // 64 d-chunks of 8
    const int d0    = chunk * DLB;

    if (tid < 256) {
        float s, c;
        sincosf(-6.283185307179586f * (float)tid * (1.0f / 1024.0f), &s, &c);
        tw[tid] = make_float2(c, s);
    }
    if (tid < 512) {
        int t2i = tid >> 7, gi = tid & 127;
        float s, c;
        sincosf(-1.5339807878856412e-03f * (float)(t2i * gi), &s, &c);  // -2pi/4096 * t2*g
        tw2[tid] = make_float2(c, s);
    }

    const int dl  = tid & 7;          // d lane
    const int g   = tid >> 3;         // k-group 0..127
    const int dp  = tid & 3;          // d-pair for the load/stage1 phase
    const int t1l = tid >> 2;         // [0,256): stage-1 butterfly row
    const int dp2 = tid & 3;          // col pair for middle stages
    const int bfm = tid >> 2;         // middle-stage butterfly id [0,256)

    float2 X1[8], Z4[8];              // X[k] and X[(4096-k)%4096], k = g + 128*j
#pragma unroll
    for (int j = 0; j < 8; ++j) {
        X1[j] = make_float2(0.f, 0.f);
        Z4[j] = make_float2(0.f, 0.f);
    }

    for (int t2 = 0; t2 < 4; ++t2) {
        // ---- issue this round's global loads BEFORE the barrier (latency drains
        //      while waiting for the last wave of the previous combine) ----
        float2 A4[4], B4[4];
#pragma unroll
        for (int it = 0; it < 4; ++it) {
            size_t off = ((size_t)(bb * LT + 4 * (t1l + 256 * it) + t2)) * ND + d0 + 2 * dp;
            A4[it] = *(const float2*)(A + off);
            B4[it] = *(const float2*)(Bp + off);
        }

        __syncthreads();  // previous round's combine reads of z done; tw/tw2 valid (rd 0)

        // ---- radix-4 stage 1 (m=256) in registers; float4 writes ----
        {
            float2 w1 = tw[t1l];
            float2 w2 = cmulf(w1, w1);
            float2 w3 = cmulf(w2, w1);
            float2 T0[2], T1[2], T2[2], T3[2];
#pragma unroll
            for (int c = 0; c < 2; ++c) {
                float2 x0 = c ? make_float2(A4[0].y, B4[0].y) : make_float2(A4[0].x, B4[0].x);
                float2 x1 = c ? make_float2(A4[1].y, B4[1].y) : make_float2(A4[1].x, B4[1].x);
                float2 x2 = c ? make_float2(A4[2].y, B4[2].y) : make_float2(A4[2].x, B4[2].x);
                float2 x3 = c ? make_float2(A4[3].y, B4[3].y) : make_float2(A4[3].x, B4[3].x);
                T0[c] = caddf(x0, x2);  T1[c] = csubf(x0, x2);
                T2[c] = caddf(x1, x3);  T3[c] = csubf(x1, x3);
            }
            const int ix = (t1l << 3) + 2 * dp;   // even float2 index -> 16B aligned
            {   // row +0: y0 = t0 + t2
                float2 ya = caddf(T0[0], T2[0]);
                float2 yb = caddf(T0[1], T2[1]);
                *(float4*)&z[ix] = make_float4(ya.x, ya.y, yb.x, yb.y);
            }
            {   // row +256: y1 = (t1 - i*t3) * w1
                float2 ya = cmulf(make_float2(T1[0].x + T3[0].y, T1[0].y - T3[0].x), w1);
                float2 yb = cmulf(make_float2(T1[1].x + T3[1].y, T1[1].y - T3[1].x), w1);
                *(float4*)&z[ix + 2048] = make_float4(ya.x, ya.y, yb.x, yb.y);
            }
            {   // row +512: y2 = (t0 - t2) * w2
                float2 ya = cmulf(csubf(T0[0], T2[0]), w2);
                float2 yb = cmulf(csubf(T0[1], T2[1]), w2);
                *(float4*)&z[ix + 4096] = make_float4(ya.x, ya.y, yb.x, yb.y);
            }
            {   // row +768: y3 = (t1 + i*t3) * w3
                float2 ya = cmulf(make_float2(T1[0].x - T3[0].y, T1[0].y + T3[0].x), w3);
                float2 yb = cmulf(make_float2(T1[1].x - T3[1].y, T1[1].y + T3[1].x), w3);
                *(float4*)&z[ix + 6144] = make_float4(ya.x, ya.y, yb.x, yb.y);
            }
        }
        __syncthreads();

        // ---- remaining radix-4 DIF stages (m = 64,16,4,1): one b128 butterfly/thread ----
        // (m=1: j=0, tw[0]=(1,0) -> generic butterfly is exact; completes the FFT.)
#pragma unroll
        for (int st = 0; st < 4; ++st) {
            const int lgm  = 6 - 2 * st;      // 6,4,2,0
            const int m    = 1 << lgm;
            const int step = 256 >> lgm;      // 1024/(4m)
            int j   = bfm & (m - 1);
            int i0  = ((bfm >> lgm) << (lgm + 2)) + j;
            int ix  = (i0 << 3) + 2 * dp2;    // float2 units, 16B aligned
            float4 a0 = *(float4*)&z[ix];
            float4 a1 = *(float4*)&z[ix + 8 * m];
            float4 a2 = *(float4*)&z[ix + 16 * m];
            float4 a3 = *(float4*)&z[ix + 24 * m];
            float4 t0 = make_float4(a0.x + a2.x, a0.y + a2.y, a0.z + a2.z, a0.w + a2.w);
            float4 t1 = make_float4(a0.x - a2.x, a0.y - a2.y, a0.z - a2.z, a0.w - a2.w);
            float4 t2v = make_float4(a1.x + a3.x, a1.y + a3.y, a1.z + a3.z, a1.w + a3.w);
            float4 t3 = make_float4(a1.x - a3.x, a1.y - a3.y, a1.z - a3.z, a1.w - a3.w);
            float2 w1 = tw[j * step];
            float2 w2 = cmulf(w1, w1);
            float2 w3 = cmulf(w2, w1);
            // y0 = t0 + t2
            *(float4*)&z[ix] = make_float4(t0.x + t2v.x, t0.y + t2v.y,
                                           t0.z + t2v.z, t0.w + t2v.w);
            {   // y1 = (t1 - i*t3) * w1
                float ax = t1.x + t3.y, ay = t1.y - t3.x;
                float bx = t1.z + t3.w, by = t1.w - t3.z;
                *(float4*)&z[ix + 8 * m] = make_float4(ax * w1.x - ay * w1.y,
                                                       ax * w1.y + ay * w1.x,
                                                       bx * w1.x - by * w1.y,
                                                       bx * w1.y + by * w1.x);
            }
            {   // y2 = (t0 - t2) * w2
                float ax = t0.x - t2v.x, ay = t0.y - t2v.y;
                float bx = t0.z - t2v.z, by = t0.w - t2v.w;
                *(float4*)&z[ix + 16 * m] = make_float4(ax * w2.x - ay * w2.y,
                                                        ax * w2.y + ay * w2.x,
                                                        bx * w2.x - by * w2.y,
                                                        bx * w2.y + by * w2.x);
            }
            {   // y3 = (t1 + i*t3) * w3
                float ax = t1.x - t3.y, ay = t1.y + t3.x;
                float bx = t1.z - t3.w, by = t1.w + t3.z;
                *(float4*)&z[ix + 24 * m] = make_float4(ax * w3.x - ay * w3.y,
                                                        ax * w3.y + ay * w3.x,
                                                        bx * w3.x - by * w3.y,
                                                        bx * w3.y + by * w3.x);
            }
            __syncthreads();
        }

        // ---- combine: X[k] += W4096^(t2*k)*Y[k]; X[4096-k] += conj(W)*Y[(1024-k)%1024] ----
        // Twiddles from tables: w0 = tw2[128 t2 + g], wstep = W4096^(128 t2) = tw[32 t2].
        float2 w     = tw2[(t2 << 7) + g];
        float2 wstep = tw[t2 << 5];
#pragma unroll
        for (int j = 0; j < 8; ++j) {
            int k   = g + 128 * j;
            int rk  = rev4_10(k);
            int k2  = (1024 - k) & 1023;
            int rk2 = rev4_10(k2);
            float2 Ya = z[(rk << 3) + dl];
            float2 Yb = z[(rk2 << 3) + dl];
            X1[j].x += w.x * Ya.x - w.y * Ya.y;
            X1[j].y += w.x * Ya.y + w.y * Ya.x;
            Z4[j].x += w.x * Yb.x + w.y * Yb.y;   // conj(w) * Yb
            Z4[j].y += w.x * Yb.y - w.y * Yb.x;
            w = cmulf(w, wstep);
        }
    }

    // ---- unpack Qa/Qb, products, reduce over 8 d-lanes, atomic flush ----
#pragma unroll
    for (int j = 0; j < 8; ++j) {
        int k = g + 128 * j;
        float Ar = 0.5f * (X1[j].x + Z4[j].x);
        float Ai = 0.5f * (X1[j].y - Z4[j].y);
        float Br = 0.5f * (X1[j].y + Z4[j].y);
        float Bi = 0.5f * (Z4[j].x - X1[j].x);
        float da = Ar * Ar + Ai * Ai;
        float db = Br * Br + Bi * Bi;
        float cr = Ar * Br + Ai * Bi;
        float ci = Ar * Bi - Ai * Br;
        for (int msk = 1; msk < DLB; msk <<= 1) {
            da += __shfl_xor(da, msk);
            db += __shfl_xor(db, msk);
            cr += __shfl_xor(cr, msk);
            ci += __shfl_xor(ci, msk);
        }
        if (dl == 0) {
            atomicAdd(&ws[0 * NB * MBINS + bb * MBINS + k], da);
            atomicAdd(&ws[1 * NB * MBINS + bb * MBINS + k], db);
            atomicAdd(&ws[2 * NB * MBINS + bb * MBINS + k], cr);
            atomicAdd(&ws[3 * NB * MBINS + bb * MBINS + k], ci);
        }
    }
}

// Inverse: block = (b, dir). S = C/den (dir 0) or conj(C)/den (dir 1), padded to 4096,
// radix-4 IFFT (conj twiddles, digit-reversed output indexing), real part.
__global__ __launch_bounds__(512)
void cte_inv_kernel(const float* __restrict__ ws, float* __restrict__ out) {
    __shared__ float2 zz[4096];       // 32 KB
    __shared__ float2 tw[1024];       // tw[e] = exp(+2*pi*i*e/4096)
    const int tid = threadIdx.x;
    const int bb  = blockIdx.x >> 1;
    const int dir = blockIdx.x & 1;

    for (int i = tid; i < 1024; i += 512) {
        float s, c;
        sincosf(6.283185307179586f * (float)i * (1.0f / 4096.0f), &s, &c);
        tw[i] = make_float2(c, s);
    }
    for (int i = tid; i < 4096; i += 512) {
        float2 v = make_float2(0.f, 0.f);
        if (i < MBINS) {
            float den = ws[(dir ? 1 : 0) * NB * MBINS + bb * MBINS + i] + LMBDA;
            float cr  = ws[2 * NB * MBINS + bb * MBINS + i];
            float ci  = ws[3 * NB * MBINS + bb * MBINS + i];
            if (dir) ci = -ci;
            v = make_float2(cr / den, ci / den);
        }
        zz[i] = v;
    }
    __syncthreads();

#pragma unroll
    for (int st = 0; st < 6; ++st) {
        const int lgm  = 10 - 2 * st;     // m = 1024,256,64,16,4,1
        const int m    = 1 << lgm;
        const int step = 1024 >> lgm;     // 4096/(4m)
#pragma unroll
        for (int r = 0; r < 2; ++r) {
            int bf = r * 512 + tid;       // butterfly id [0,1024)
            int j  = bf & (m - 1);
            int i0 = ((bf >> lgm) << (lgm + 2)) + j;
            float2 a0 = zz[i0], a1 = zz[i0 + m], a2 = zz[i0 + 2 * m], a3 = zz[i0 + 3 * m];
            float2 t0  = caddf(a0, a2), t1v = csubf(a0, a2);
            float2 t2v = caddf(a1, a3), t3  = csubf(a1, a3);
            float2 y0 = caddf(t0, t2v);
            float2 y2 = csubf(t0, t2v);
            float2 y1 = make_float2(t1v.x - t3.y, t1v.y + t3.x);   // t1 + i*t3 (inverse)
            float2 y3 = make_float2(t1v.x + t3.y, t1v.y - t3.x);   // t1 - i*t3
            if (m > 1) {
                float2 w1 = tw[j * step];
                float2 w2 = cmulf(w1, w1);
                float2 w3 = cmulf(w2, w1);
                y1 = cmulf(y1, w1);
                y2 = cmulf(y2, w2);
                y3 = cmulf(y3, w3);
            }
            zz[i0] = y0; zz[i0 + m] = y1; zz[i0 + 2 * m] = y2; zz[i0 + 3 * m] = y3;
        }
        __syncthreads();
    }

    const float scale = 1.0f / 4096.0f;
    for (int t = tid; t < 4096; t += 512) {
        int rt = rev4_12(t);              // R[t] sits at digit-reversed slot
        float val = zz[rt].x * scale;
        int col = (dir == 0) ? (4095 - t) : (4096 + t);
        out[(size_t)bb * 8192 + col] = val;
    }
}

extern "C" void kernel_launch(void* const* d_in, const int* in_sizes, int n_in,
                              void* d_out, int out_size, void* d_ws, size_t ws_size,
                              hipStream_t stream) {
    const float* a = (const float*)d_in[0];
    const float* b = (const float*)d_in[1];
    // d_in[2] (offsets) only determines shapes; numerically unused.
    float* out = (float*)d_out;
    float* ws  = (float*)d_ws;

    hipMemsetAsync(d_ws, 0, 4 * NB * MBINS * sizeof(float), stream);
    cte_fwd_kernel<<<dim3(NB * (ND / DLB)), dim3(FWD_THREADS), 0, stream>>>(a, b, ws);
    cte_inv_kernel<<<dim3(NB * 2), dim3(512), 0, stream>>>(ws, out);
}